// Round 7
// baseline (1797.430 us; speedup 1.0000x reference)
//
#include <hip/hip_runtime.h>
#include <stdint.h>

typedef unsigned short u16;
typedef __attribute__((ext_vector_type(8))) __bf16 bf16x8;
typedef __attribute__((ext_vector_type(4))) float f32x4;

#define TTS 256
#define NSEG 1024
#define TC 32            // time-chunk for gates

__device__ __forceinline__ u16 f2bf(float f) {
  union { float f; uint32_t u; } v; v.f = f;
  uint32_t r = v.u + 0x7fffu + ((v.u >> 16) & 1u);
  return (u16)(r >> 16);
}
__device__ __forceinline__ float bf2f(u16 h) {
  union { uint32_t u; float f; } v; v.u = ((uint32_t)h) << 16;
  return v.f;
}
__device__ __forceinline__ float sigm(float x) {
  return __builtin_amdgcn_rcpf(1.0f + __expf(-x));
}

// ---------------- K0: transpose small weight, fp32 -> bf16 ----------------
__global__ void k_transp(const float* __restrict__ in, u16* __restrict__ out, int R, int C) {
  int i = blockIdx.x * blockDim.x + threadIdx.x;
  if (i < R * C) {
    int r = i / C, c = i % C;
    out[(size_t)c * R + r] = f2bf(in[i]);
  }
}

// ---------------- K1/K3c: bf16 MFMA GEMM, 128x128 tile, BK=32 ----------------
// AMODE 0: A fp32 row-major [M][K] (K1: x), convert in-register.
// AMODE 1: A bf16 chunked x_att [seg][k>>6][t][64], rows m = seg*TC + tt, t = t0+tt.
// STORE_T: write chunked convT layout [seg][f>>6][f&63][t]. Else row-major [M][Nld].
template <bool RELU, bool STORE_T, int AMODE>
__global__ __launch_bounds__(256) void k_gemm(
    const void* __restrict__ Av, const u16* __restrict__ Bt,
    const float* __restrict__ bias, u16* __restrict__ out, int K, int Nld, int t0) {
  __shared__ u16 ldsA[4096];
  __shared__ u16 ldsB[4096];
  const int tid  = threadIdx.x;
  const int w    = tid >> 6;
  const int lane = tid & 63;
  const int quad = lane >> 4;
  const int l16  = lane & 15;
  const int m0 = blockIdx.x * 128;
  const int n0 = blockIdx.y * 128;
  const int wm = w >> 1, wn = w & 1;
  const int srow = tid & 127, shalf = tid >> 7;   // staging map

  f32x4 acc[4][4];
#pragma unroll
  for (int i = 0; i < 4; i++)
#pragma unroll
    for (int j = 0; j < 4; j++) acc[i][j] = f32x4{0.f, 0.f, 0.f, 0.f};

  for (int k0 = 0; k0 < K; k0 += 32) {
    ushort4 va[2][2]; bf16x8 vb[2];
#pragma unroll
    for (int q = 0; q < 2; q++) {
      int c = shalf * 2 + q;
      int kk = k0 + c * 8;
      if (AMODE == 0) {
        const float* Af = (const float*)Av;
        float4 f0 = *(const float4*)(Af + (size_t)(m0 + srow) * K + kk);
        float4 f1 = *(const float4*)(Af + (size_t)(m0 + srow) * K + kk + 4);
        va[q][0] = ushort4{f2bf(f0.x), f2bf(f0.y), f2bf(f0.z), f2bf(f0.w)};
        va[q][1] = ushort4{f2bf(f1.x), f2bf(f1.y), f2bf(f1.z), f2bf(f1.w)};
      } else {
        const u16* Ax = (const u16*)Av;
        int r = m0 + srow;
        const bf16x8 v = *(const bf16x8*)(Ax + (size_t)(r >> 5) * 65536 +
                          (size_t)(kk >> 6) * 16384 + (t0 + (r & 31)) * 64 + (kk & 63));
        va[q][0] = ((const ushort4*)&v)[0];
        va[q][1] = ((const ushort4*)&v)[1];
      }
      vb[q] = *(const bf16x8*)(Bt + (size_t)(n0 + srow) * K + kk);
    }
    __syncthreads();  // prior iteration's ds_reads complete before overwrite
#pragma unroll
    for (int q = 0; q < 2; q++) {
      int c = shalf * 2 + q;
      *(ushort4*)&ldsA[(c * 128 + srow) * 8]     = va[q][0];
      *(ushort4*)&ldsA[(c * 128 + srow) * 8 + 4] = va[q][1];
      *(bf16x8*)&ldsB[(c * 128 + srow) * 8] = vb[q];
    }
    __syncthreads();
    bf16x8 a[4], b[4];
#pragma unroll
    for (int i = 0; i < 4; i++)
      a[i] = *(const bf16x8*)&ldsA[(quad * 128 + wm * 64 + i * 16 + l16) * 8];
#pragma unroll
    for (int j = 0; j < 4; j++)
      b[j] = *(const bf16x8*)&ldsB[(quad * 128 + wn * 64 + j * 16 + l16) * 8];
#pragma unroll
    for (int i = 0; i < 4; i++)
#pragma unroll
      for (int j = 0; j < 4; j++)
        acc[i][j] = __builtin_amdgcn_mfma_f32_16x16x32_bf16(a[i], b[j], acc[i][j], 0, 0, 0);
  }

#pragma unroll
  for (int j = 0; j < 4; j++) {
    int col = n0 + wn * 64 + j * 16 + l16;
    float bv = bias[col];
#pragma unroll
    for (int i = 0; i < 4; i++) {
      int row0 = m0 + wm * 64 + i * 16 + quad * 4;  // 4 consecutive rows
      if (STORE_T) {
        int nseg = row0 >> 8, tt0 = row0 & 255;
        ushort4 o;
        float v0 = acc[i][j][0] + bv, v1 = acc[i][j][1] + bv;
        float v2 = acc[i][j][2] + bv, v3 = acc[i][j][3] + bv;
        if (RELU) {
          v0 = fmaxf(v0, 0.f); v1 = fmaxf(v1, 0.f);
          v2 = fmaxf(v2, 0.f); v3 = fmaxf(v3, 0.f);
        }
        o.x = f2bf(v0); o.y = f2bf(v1); o.z = f2bf(v2); o.w = f2bf(v3);
        *(ushort4*)&out[(size_t)nseg * 65536 + (size_t)(col >> 6) * 16384 +
                        (col & 63) * 256 + tt0] = o;
      } else {
#pragma unroll
        for (int r = 0; r < 4; r++) {
          float v = acc[i][j][r] + bv;
          if (RELU) v = fmaxf(v, 0.f);
          out[(size_t)(row0 + r) * Nld + col] = f2bf(v);
        }
      }
    }
  }
}

// ---------------- K2: attention (in-place on xac) ----------------
// v2: Wt A-fragments register-resident (loop-invariant per block, L2-hit
// scattered 16B loads, once per block); ldsC only (34 KB); 3 barriers total.
__global__ __launch_bounds__(256) void k_attn(
    u16* xac,
    const u16* __restrict__ Wt,       // attn_w^T: [t'][t] 256x256
    const float* __restrict__ attn_b) {
  __shared__ u16 ldsC[16384];         // conv resident [tchunk 32][f 64][8]
  __shared__ float redmax[4][64];
  __shared__ float redsum[4][64];
  const int tid  = threadIdx.x;
  const int w    = tid >> 6;
  const int lane = tid & 63;
  const int quad = lane >> 4;
  const int l16  = lane & 15;
  const int seg = blockIdx.x;
  const int c4  = blockIdx.y;
  u16* reg = xac + (size_t)seg * 65536 + (size_t)c4 * 16384;

  // Wt A-fragments -> VGPR (32 frags = 128 VGPR); rows w*64+i*16+l16, k s*32+quad*8
  bf16x8 wfrag[4][8];
#pragma unroll
  for (int i = 0; i < 4; i++)
#pragma unroll
    for (int s = 0; s < 8; s++)
      wfrag[i][s] = *(const bf16x8*)(Wt + (size_t)(w * 64 + i * 16 + l16) * 256 +
                                     s * 32 + quad * 8);

  // stage conv fully: thread (f = tid&63, g = tid>>6) copies 8 chunks
  {
    const int f = tid & 63, g = tid >> 6;
#pragma unroll
    for (int u = 0; u < 8; u++) {
      int tch = g * 8 + u;
      *(bf16x8*)&ldsC[(tch * 64 + f) * 8] =
          *(const bf16x8*)(reg + (size_t)f * 256 + tch * 8);
    }
  }
  __syncthreads();

  f32x4 acc[4][4];
#pragma unroll
  for (int i = 0; i < 4; i++)
#pragma unroll
    for (int j = 0; j < 4; j++) acc[i][j] = f32x4{0.f, 0.f, 0.f, 0.f};

#pragma unroll
  for (int s = 0; s < 8; s++) {
    bf16x8 b[4];
#pragma unroll
    for (int j = 0; j < 4; j++)
      b[j] = *(const bf16x8*)&ldsC[((s * 4 + quad) * 64 + j * 16 + l16) * 8];
#pragma unroll
    for (int i = 0; i < 4; i++)
#pragma unroll
      for (int j = 0; j < 4; j++)
        acc[i][j] = __builtin_amdgcn_mfma_f32_16x16x32_bf16(wfrag[i][s], b[j], acc[i][j], 0, 0, 0);
  }

  // + attn_b[t']
#pragma unroll
  for (int i = 0; i < 4; i++)
#pragma unroll
    for (int r = 0; r < 4; r++) {
      float ab = attn_b[w * 64 + i * 16 + quad * 4 + r];
#pragma unroll
      for (int j = 0; j < 4; j++) acc[i][j][r] += ab;
    }

  // softmax over t' (rows) per f column
  float lmax[4];
#pragma unroll
  for (int j = 0; j < 4; j++) {
    float m = -1e30f;
#pragma unroll
    for (int i = 0; i < 4; i++)
#pragma unroll
      for (int r = 0; r < 4; r++) m = fmaxf(m, acc[i][j][r]);
    m = fmaxf(m, __shfl_xor(m, 16));
    m = fmaxf(m, __shfl_xor(m, 32));
    lmax[j] = m;
  }
  if (quad == 0) {
#pragma unroll
    for (int j = 0; j < 4; j++) redmax[w][j * 16 + l16] = lmax[j];
  }
  __syncthreads();
  float gmax[4];
#pragma unroll
  for (int j = 0; j < 4; j++) {
    int c = j * 16 + l16;
    gmax[j] = fmaxf(fmaxf(redmax[0][c], redmax[1][c]), fmaxf(redmax[2][c], redmax[3][c]));
  }
  float lsum[4];
#pragma unroll
  for (int j = 0; j < 4; j++) {
    float sacc = 0.f;
#pragma unroll
    for (int i = 0; i < 4; i++)
#pragma unroll
      for (int r = 0; r < 4; r++) {
        float e = __expf(acc[i][j][r] - gmax[j]);
        acc[i][j][r] = e;
        sacc += e;
      }
    sacc += __shfl_xor(sacc, 16);
    sacc += __shfl_xor(sacc, 32);
    lsum[j] = sacc;
  }
  if (quad == 0) {
#pragma unroll
    for (int j = 0; j < 4; j++) redsum[w][j * 16 + l16] = lsum[j];
  }
  __syncthreads();
  float rinv[4];
#pragma unroll
  for (int j = 0; j < 4; j++) {
    int c = j * 16 + l16;
    rinv[j] = 1.0f / (redsum[0][c] + redsum[1][c] + redsum[2][c] + redsum[3][c]);
  }

  // x_att[t][f] = conv[t][f] * probs[f][t]; overwrite own region
#pragma unroll
  for (int i = 0; i < 4; i++) {
#pragma unroll
    for (int r = 0; r < 4; r++) {
      int tp = w * 64 + i * 16 + quad * 4 + r;
#pragma unroll
      for (int j = 0; j < 4; j++) {
        int fl = j * 16 + l16;
        float cv = bf2f(ldsC[((tp >> 3) * 64 + fl) * 8 + (tp & 7)]);
        float xa = acc[i][j][r] * rinv[j] * cv;
        reg[(size_t)tp * 64 + fl] = f2bf(xa);
      }
    }
  }
}

// ---------------- K4c v2: GRU scan over one time chunk (TC steps) ----------------
// 64 blocks x 512 thr, 16 segs/block. ALL Ut B-fragments out of LDS:
// 4 sets VGPR-resident (128 regs), 2 sets streamed from L2 per step with a
// rolling 4-deep window. LDS = h only (8 ds_read_b128/wave/step).
// h carried between chunks via hio (= d_out) in fp32.
__global__ __launch_bounds__(512, 2) void k_scanc(
    const u16* __restrict__ gc,   // gates chunk [NSEG*TC][768] (x@W + bi)
    const u16* __restrict__ Ut,   // gru_u^T [768][256]
    const float* __restrict__ br, // gru_b[1]: [768]
    float* __restrict__ hio,      // [NSEG][256] fp32 (d_out)
    int init) {
  __shared__ u16 hb[16 * 264];    // bf16 h, row stride 264
  const int tid  = threadIdx.x;
  const int w    = tid >> 6;
  const int lane = tid & 63;
  const int quad = lane >> 4;
  const int l16  = lane & 15;
  const int n0 = blockIdx.x * 16;
  const int cg0 = w, cg1 = 8 + w; // two col-groups per wave

  // register-resident Ut fragments: grp0 z,r,h + grp1 h (128 VGPR)
  bf16x8 ur0[3][8], urh1[8];
#pragma unroll
  for (int g = 0; g < 3; g++)
#pragma unroll
    for (int s = 0; s < 8; s++)
      ur0[g][s] = *(const bf16x8*)(Ut + (size_t)(g * 256 + cg0 * 16 + l16) * 256 + s * 32 + quad * 8);
#pragma unroll
  for (int s = 0; s < 8; s++)
    urh1[s] = *(const bf16x8*)(Ut + (size_t)(512 + cg1 * 16 + l16) * 256 + s * 32 + quad * 8);

  // streamed-set base pointers (grp1 z, r); L2-resident, h-independent
  const u16* pz1 = Ut + (size_t)(cg1 * 16 + l16) * 256 + quad * 8;
  const u16* pr1 = Ut + (size_t)(256 + cg1 * 16 + l16) * 256 + quad * 8;

  // biases per (group, gate)
  float brZ[2], brR[2], brH[2];
  {
    int c0 = cg0 * 16 + l16, c1 = cg1 * 16 + l16;
    brZ[0] = br[c0];       brZ[1] = br[c1];
    brR[0] = br[256 + c0]; brR[1] = br[256 + c1];
    brH[0] = br[512 + c0]; brH[1] = br[512 + c1];
  }

  // h init: registers (this lane's 4 segs x 2 groups) + hb for all 16 segs
  float hreg[2][4];
#pragma unroll
  for (int grp = 0; grp < 2; grp++)
#pragma unroll
    for (int r = 0; r < 4; r++) {
      int c = (grp ? cg1 : cg0) * 16 + l16;
      hreg[grp][r] = init ? 0.f : hio[(size_t)(n0 + quad * 4 + r) * 256 + c];
    }
  {
    int sg = tid >> 5, c0 = (tid & 31) * 8;   // 16 segs x 256 cols / 512 thr
    if (init) {
      *(ushort4*)&hb[sg * 264 + c0]     = ushort4{0, 0, 0, 0};
      *(ushort4*)&hb[sg * 264 + c0 + 4] = ushort4{0, 0, 0, 0};
    } else {
      const float* hp = hio + (size_t)(n0 + sg) * 256 + c0;
      float4 h0 = *(const float4*)(hp), h1 = *(const float4*)(hp + 4);
      *(ushort4*)&hb[sg * 264 + c0]     = ushort4{f2bf(h0.x), f2bf(h0.y), f2bf(h0.z), f2bf(h0.w)};
      *(ushort4*)&hb[sg * 264 + c0 + 4] = ushort4{f2bf(h1.x), f2bf(h1.y), f2bf(h1.z), f2bf(h1.w)};
    }
  }
  // gates row bases for this lane's 4 segs
  const u16* gseg[4];
#pragma unroll
  for (int r = 0; r < 4; r++)
    gseg[r] = gc + (size_t)(n0 + quad * 4 + r) * TC * 768;
  __syncthreads();

  for (int tt = 0; tt < TC; tt++) {
    // prefetch gates[tt] (h-independent)
    float gg[2][3][4];
#pragma unroll
    for (int grp = 0; grp < 2; grp++)
#pragma unroll
      for (int g = 0; g < 3; g++)
#pragma unroll
        for (int r = 0; r < 4; r++) {
          int c = (grp ? cg1 : cg0) * 16 + l16;
          gg[grp][g][r] = bf2f(gseg[r][tt * 768 + g * 256 + c]);
        }

    // rolling window: streamed grp1 z,r frags, 4 slots
    bf16x8 uz1[4], ur1[4];
#pragma unroll
    for (int s = 0; s < 4; s++) {
      uz1[s] = *(const bf16x8*)(pz1 + s * 32);
      ur1[s] = *(const bf16x8*)(pr1 + s * 32);
    }

    f32x4 acc[2][3];
#pragma unroll
    for (int grp = 0; grp < 2; grp++)
#pragma unroll
      for (int g = 0; g < 3; g++) acc[grp][g] = f32x4{0.f, 0.f, 0.f, 0.f};

#pragma unroll
    for (int s = 0; s < 8; s++) {
      bf16x8 ah = *(const bf16x8*)&hb[l16 * 264 + s * 32 + quad * 8];
#pragma unroll
      for (int g = 0; g < 3; g++)
        acc[0][g] = __builtin_amdgcn_mfma_f32_16x16x32_bf16(ah, ur0[g][s], acc[0][g], 0, 0, 0);
      acc[1][0] = __builtin_amdgcn_mfma_f32_16x16x32_bf16(ah, uz1[s & 3],  acc[1][0], 0, 0, 0);
      acc[1][1] = __builtin_amdgcn_mfma_f32_16x16x32_bf16(ah, ur1[s & 3],  acc[1][1], 0, 0, 0);
      acc[1][2] = __builtin_amdgcn_mfma_f32_16x16x32_bf16(ah, urh1[s],     acc[1][2], 0, 0, 0);
      if (s < 4) {   // refill slot s with chunk s+4
        uz1[s] = *(const bf16x8*)(pz1 + (s + 4) * 32);
        ur1[s] = *(const bf16x8*)(pr1 + (s + 4) * 32);
      }
    }
    __syncthreads();   // all hb reads complete before overwrite

#pragma unroll
    for (int grp = 0; grp < 2; grp++)
#pragma unroll
      for (int r = 0; r < 4; r++) {
        int c = (grp ? cg1 : cg0) * 16 + l16;
        float z  = sigm(acc[grp][0][r] + gg[grp][0][r] + brZ[grp]);
        float rg = sigm(acc[grp][1][r] + gg[grp][1][r] + brR[grp]);
        float hh = fmaxf(gg[grp][2][r] + rg * (acc[grp][2][r] + brH[grp]), 0.f);
        float hn = z * hreg[grp][r] + (1.0f - z) * hh;
        hreg[grp][r] = hn;
        hb[(quad * 4 + r) * 264 + c] = f2bf(hn);
      }
    __syncthreads();   // writes visible before next step's reads
  }

#pragma unroll
  for (int grp = 0; grp < 2; grp++)
#pragma unroll
    for (int r = 0; r < 4; r++) {
      int c = (grp ? cg1 : cg0) * 16 + l16;
      hio[(size_t)(n0 + quad * 4 + r) * 256 + c] = hreg[grp][r];
    }
}

// ---------------- host ----------------
extern "C" void kernel_launch(void* const* d_in, const int* in_sizes, int n_in,
                              void* d_out, int out_size, void* d_ws, size_t ws_size,
                              hipStream_t stream) {
  (void)in_sizes; (void)n_in; (void)out_size;
  const float* x      = (const float*)d_in[0];
  const float* conv_w = (const float*)d_in[1];
  const float* conv_b = (const float*)d_in[2];
  const float* attn_w = (const float*)d_in[3];
  const float* attn_b = (const float*)d_in[4];
  const float* gru_w  = (const float*)d_in[5];
  const float* gru_u  = (const float*)d_in[6];
  const float* gru_b  = (const float*)d_in[7];

  // scratch layout: 185,532,416 B total (known-safe)
  const size_t NEEDED = 185532416;
  if (ws_size < NEEDED) return;
  char* ws = (char*)d_ws;
  u16* xac     = (u16*)(ws);                  // 134217728 B: convT then x_att (chunked, in-place)
  u16* gatesC  = (u16*)(ws + 134217728);      //  50331648 B: gates for one 32-step chunk
  u16* conv_wT = (u16*)(ws + 184549376);      //     65536 B [f][c]
  u16* attn_wT = (u16*)(ws + 184614912);      //    131072 B [t'][t]
  u16* gru_wT  = (u16*)(ws + 184745984);      //    393216 B [j][f]
  u16* gru_uT  = (u16*)(ws + 185139200);      //    393216 B [j][k]

  hipLaunchKernelGGL(k_transp, dim3(128), dim3(256), 0, stream, conv_w, conv_wT, 128, 256);
  hipLaunchKernelGGL(k_transp, dim3(256), dim3(256), 0, stream, attn_w, attn_wT, 256, 256);
  hipLaunchKernelGGL(k_transp, dim3(768), dim3(256), 0, stream, gru_w, gru_wT, 256, 768);
  hipLaunchKernelGGL(k_transp, dim3(768), dim3(256), 0, stream, gru_u, gru_uT, 256, 768);

  // K1: conv = relu(x @ conv_w + b), fp32 A read + in-register bf16 convert
  hipLaunchKernelGGL((k_gemm<true, true, 0>), dim3(2048, 2), dim3(256), 0, stream,
                     (const void*)x, conv_wT, conv_b, xac, 128, 0, 0);
  // K2: attention softmax + multiply, in place on xac
  hipLaunchKernelGGL(k_attn, dim3(1024, 4), dim3(256), 0, stream,
                     xac, attn_wT, attn_b);
  // K3c/K4c: 8 time chunks of (gates GEMM -> 32-step scan); h lives in d_out
  for (int c = 0; c < 8; c++) {
    hipLaunchKernelGGL((k_gemm<false, false, 1>), dim3(256, 6), dim3(256), 0, stream,
                       (const void*)xac, gru_wT, gru_b, gatesC, 256, 768, c * TC);
    hipLaunchKernelGGL(k_scanc, dim3(64), dim3(512), 0, stream,
                       gatesC, gru_uT, gru_b + 768, (float*)d_out, c == 0 ? 1 : 0);
  }
}